// Round 9
// baseline (563.243 us; speedup 1.0000x reference)
//
#include <hip/hip_runtime.h>

#define NB 4
#define P 1024
#define ITERS 50
#define WPB 16              // workgroups per batch
#define THREADS 1024
#define WAVES 16
#define K_COEF (-14.426950408889634f)   // -log2(e)/eps, eps=0.1
#define INV_KCOEF (-0.06931471805599453f) // 1/K_COEF = -eps*ln2
#define DELTA 1e-8f
#define SCALE 274877906944.0f           // 2^38 fixed-point scale
#define M56 0x00FFFFFFFFFFFFFFull
#define CNT_ONE (1ull << 56)

typedef unsigned long long u64;
typedef unsigned int u32;

// ws: [0, 1.6MB) z[NB][ITERS][P] u64 (arrivals<<56 | fixed-point sum)
//     [+0KB) a_ws[NB][P] f32 | [+16KB) b_ws[NB][P] f32

__global__ void sink_zero(u64* z, float* out) {
    int t = blockIdx.x * 1024 + threadIdx.x;
    if (t < NB * ITERS * P) z[t] = 0ull;
    if (t < NB) out[t] = 0.0f;
}

__global__ __launch_bounds__(THREADS, 1)
void sink_main(const float* __restrict__ mu, const float* __restrict__ nu,
               const float* __restrict__ C, float* __restrict__ out,
               u64* __restrict__ z, float* __restrict__ a_ws,
               float* __restrict__ b_ws) {
    const int n   = blockIdx.x >> 4;   // batch
    const int w   = blockIdx.x & 15;   // wg within batch
    const int tid = threadIdx.x;
    const int wq  = tid >> 6;          // wave 0..15
    const int l   = tid & 63;          // lane

    u64* zb = z + (size_t)n * ITERS * P;
    const float* Cb = C + (size_t)n * P * P;
    const int base = w * 64 + wq * 4;  // this wave's first row

    float Kr[4][16], muv[4], b_r[16], a_own[4];

    // Kr[q][k] = K[base+q][l+64k]  (each load: 64 lanes x 4B = 256B coalesced)
    #pragma unroll
    for (int q = 0; q < 4; ++q) {
        const int r = base + q;
        #pragma unroll
        for (int k = 0; k < 16; ++k)
            Kr[q][k] = exp2f(K_COEF * Cb[(size_t)r * P + l + 64 * k]);
        muv[q] = mu[n * P + r] + DELTA;
    }
    const float nuv_s = (nu[n * P + tid] + DELTA) * SCALE;  // own column = tid

    __shared__ float bs[P];            // 4KB  : broadcast b
    __shared__ float zs[WAVES][P];     // 64KB : per-wave column partials

    #pragma unroll
    for (int k = 0; k < 16; ++k) b_r[k] = 1.0f;   // v=0 -> b=1

    for (int t = 0; t < ITERS; ++t) {
        // a_i = (mu_i+d) / sum_j K_ij b_j   (own rows, never published)
        #pragma unroll
        for (int q = 0; q < 4; ++q) {
            float y = 0.f;
            #pragma unroll
            for (int k = 0; k < 16; ++k) y += Kr[q][k] * b_r[k];
            #pragma unroll
            for (int off = 32; off > 0; off >>= 1) y += __shfl_xor(y, off, 64);
            a_own[q] = muv[q] / y;
        }
        // per-wave column partials
        #pragma unroll
        for (int k = 0; k < 16; ++k)
            zs[wq][l + 64 * k] = Kr[0][k] * a_own[0] + Kr[1][k] * a_own[1]
                               + Kr[2][k] * a_own[2] + Kr[3][k] * a_own[3];
        __syncthreads();
        // WG reduce (16 waves) -> ONE tagged fixed-point RMW per column per WG
        float red = 0.f;
        #pragma unroll
        for (int g = 0; g < WAVES; ++g) red += zs[g][tid];
        u64* zt = zb + (size_t)t * P;
        const u64 own = CNT_ONE + (u64)(red * SCALE);
        u64 v = __hip_atomic_fetch_add(&zt[tid], own, __ATOMIC_RELAXED,
                                       __HIP_MEMORY_SCOPE_AGENT) + own;
        // poll own column word: count in top byte, sum in low 56 bits
        while ((v >> 56) != (u64)WPB) {
            __builtin_amdgcn_s_sleep(1);
            v = __hip_atomic_load(&zt[tid], __ATOMIC_RELAXED,
                                  __HIP_MEMORY_SCOPE_AGENT);
        }
        bs[tid] = nuv_s / (float)(v & M56);   // b_j = nu_j / z_j
        __syncthreads();
        #pragma unroll
        for (int k = 0; k < 16; ++k) b_r[k] = bs[l + 64 * k];
        // no further barrier: poll-pass at t+1 transitively implies all WGs
        // passed this iteration's barriers.
    }

    // publish a (own 4 rows per wave) and b (one WG per batch); kernel-boundary
    // release makes plain stores visible to sink_epi.
    if (l == 0) {
        #pragma unroll
        for (int q = 0; q < 4; ++q) a_ws[n * P + base + q] = a_own[q];
    }
    if (w == 0) b_ws[n * P + tid] = bs[tid];

    // cost only: c reconstructed from Kr (log2 roundtrip err ~1e-6 << 2e-2)
    float costp = 0.f;
    #pragma unroll
    for (int q = 0; q < 4; ++q) {
        #pragma unroll
        for (int k = 0; k < 16; ++k) {
            const float c = __log2f(Kr[q][k]) * INV_KCOEF;
            costp += a_own[q] * Kr[q][k] * b_r[k] * c;
        }
    }
    #pragma unroll
    for (int off = 32; off > 0; off >>= 1) costp += __shfl_xor(costp, off, 64);
    __syncthreads();               // bs free for reuse
    if (l == 0) bs[wq] = costp;
    __syncthreads();
    if (tid == 0) {
        float s = 0.f;
        #pragma unroll
        for (int g = 0; g < WAVES; ++g) s += bs[g];
        atomicAdd(&out[n], s);
    }
}

// full-device epilogue: pi = a_i K_ij b_j ; out_C = C  (48MB at device BW)
__global__ __launch_bounds__(256)
void sink_epi(const float* __restrict__ C, const float* __restrict__ a_ws,
              const float* __restrict__ b_ws, float* __restrict__ out) {
    const size_t f = ((size_t)blockIdx.x * 256 + threadIdx.x) * 4;
    const int n  = (int)(f >> 20);
    const int r  = (int)((f >> 10) & 1023);
    const int j0 = (int)(f & 1023);

    const float a = a_ws[n * P + r];
    const float4 b4 = *reinterpret_cast<const float4*>(b_ws + n * P + j0);
    const float4 c4 = *reinterpret_cast<const float4*>(C + f);

    float4 p4;
    p4.x = a * exp2f(K_COEF * c4.x) * b4.x;
    p4.y = a * exp2f(K_COEF * c4.y) * b4.y;
    p4.z = a * exp2f(K_COEF * c4.z) * b4.z;
    p4.w = a * exp2f(K_COEF * c4.w) * b4.w;

    float* out_pi = out + 4;
    float* out_C  = out + 4 + (size_t)NB * P * P;
    *reinterpret_cast<float4*>(out_pi + f) = p4;
    *reinterpret_cast<float4*>(out_C + f)  = c4;
}

extern "C" void kernel_launch(void* const* d_in, const int* in_sizes, int n_in,
                              void* d_out, int out_size, void* d_ws, size_t ws_size,
                              hipStream_t stream) {
    const float* mu = (const float*)d_in[0];
    const float* nu = (const float*)d_in[1];
    const float* C  = (const float*)d_in[2];
    float* out = (float*)d_out;
    u64* zws = (u64*)d_ws;                                   // 1.6 MB
    float* a_ws = (float*)((char*)d_ws + (size_t)NB * ITERS * P * 8);
    float* b_ws = a_ws + NB * P;

    sink_zero<<<(NB * ITERS * P + 1023) / 1024, 1024, 0, stream>>>(zws, out);
    sink_main<<<NB * WPB, THREADS, 0, stream>>>(mu, nu, C, out, zws, a_ws, b_ws);
    sink_epi<<<(NB * P * P) / (256 * 4), 256, 0, stream>>>(C, a_ws, b_ws, out);
}

// Round 10
// 221.597 us; speedup vs baseline: 2.5417x; 2.5417x over previous
//
#include <hip/hip_runtime.h>

#define NB 4
#define P 1024
#define ITERS 50
#define WPB 16              // workgroups per batch
#define THREADS 1024
#define WAVES 16
#define K_COEF (-14.426950408889634f)  // -log2(e)/eps, eps=0.1
#define DELTA 1e-8f
#define SCALE 274877906944.0f          // 2^38 fixed-point scale
#define M56 0x00FFFFFFFFFFFFFFull
#define CNT_ONE (1ull << 56)

typedef unsigned long long u64;
typedef unsigned int u32;

// ws layout: [0, 1.6MB) z[NB][ITERS][P] u64 : (arrivals<<56) | fixed-point sum

__global__ void sink_zero(u64* z, float* out) {
    size_t t = (size_t)blockIdx.x * 1024 + threadIdx.x;
    if (t < (size_t)NB * ITERS * P) z[t] = 0ull;
    if (t < NB) out[t] = 0.0f;
}

__global__ __launch_bounds__(THREADS, 4)
void sink_main(const float* __restrict__ mu, const float* __restrict__ nu,
               const float* __restrict__ C, float* __restrict__ out,
               u64* __restrict__ z) {
    const int n   = blockIdx.x >> 4;   // batch
    const int w   = blockIdx.x & 15;   // wg within batch
    const int tid = threadIdx.x;
    const int wq  = tid >> 6;          // wave 0..15
    const int l   = tid & 63;          // lane

    u64* zb = z + (size_t)n * ITERS * P;
    const float* Cb = C + (size_t)n * P * P;
    const int base = w * 64 + wq * 4;  // this wave's first row

    float Kr[4][16], muv[4], b_r[16], a_own[4];

    // Kr[q][k] = K[base+q][l+64k]  (each load: 64 lanes x 4B = 256B coalesced)
    #pragma unroll
    for (int q = 0; q < 4; ++q) {
        const int r = base + q;
        #pragma unroll
        for (int k = 0; k < 16; ++k)
            Kr[q][k] = exp2f(K_COEF * Cb[(size_t)r * P + l + 64 * k]);
        muv[q] = mu[n * P + r] + DELTA;
    }
    // this thread's own column = tid
    const float nuv_s = (nu[n * P + tid] + DELTA) * SCALE;

    __shared__ float bs[P];            // 4KB  : broadcast b
    __shared__ float zs[WAVES][P];     // 64KB : per-wave column partials

    #pragma unroll
    for (int k = 0; k < 16; ++k) b_r[k] = 1.0f;   // v=0 -> b=1

    for (int t = 0; t < ITERS; ++t) {
        // a_i = (mu_i+d) / sum_j K_ij b_j   (own rows, never published)
        #pragma unroll
        for (int q = 0; q < 4; ++q) {
            float y = 0.f;
            #pragma unroll
            for (int k = 0; k < 16; ++k) y += Kr[q][k] * b_r[k];
            #pragma unroll
            for (int off = 32; off > 0; off >>= 1) y += __shfl_xor(y, off, 64);
            a_own[q] = muv[q] / y;
        }
        // per-wave column partials
        #pragma unroll
        for (int k = 0; k < 16; ++k)
            zs[wq][l + 64 * k] = Kr[0][k] * a_own[0] + Kr[1][k] * a_own[1]
                               + Kr[2][k] * a_own[2] + Kr[3][k] * a_own[3];
        __syncthreads();
        // WG reduce (16 waves) -> ONE tagged fixed-point RMW per column per WG
        float red = 0.f;
        #pragma unroll
        for (int g = 0; g < WAVES; ++g) red += zs[g][tid];
        u64* zt = zb + (size_t)t * P;
        const u64 own = CNT_ONE + (u64)(red * SCALE);
        u64 v = __hip_atomic_fetch_add(&zt[tid], own, __ATOMIC_RELAXED,
                                       __HIP_MEMORY_SCOPE_AGENT) + own;
        // poll own column word: count in top byte, sum in low 56 bits
        while ((v >> 56) != (u64)WPB) {
            __builtin_amdgcn_s_sleep(1);
            v = __hip_atomic_load(&zt[tid], __ATOMIC_RELAXED,
                                  __HIP_MEMORY_SCOPE_AGENT);
        }
        bs[tid] = nuv_s / (float)(v & M56);   // b_j = nu_j / z_j
        __syncthreads();
        #pragma unroll
        for (int k = 0; k < 16; ++k) b_r[k] = bs[l + 64 * k];
        // NOTE: no further barrier needed — poll-pass at t+1 transitively
        // implies every thread of every WG passed this iteration's barriers.
    }

    // fused epilogue: pi = a_i K_ij b_j ; cost = sum pi*C ; copy C through
    float* out_pi = out + 4;
    float* out_C  = out + 4 + (size_t)NB * P * P;
    float costp = 0.f;
    #pragma unroll
    for (int q = 0; q < 4; ++q) {
        const int r = base + q;
        const size_t rowoff = (size_t)n * P * P + (size_t)r * P;
        #pragma unroll
        for (int k = 0; k < 16; ++k) {
            const int j = l + 64 * k;
            const float c = Cb[(size_t)r * P + j];
            const float p = a_own[q] * Kr[q][k] * b_r[k];
            out_pi[rowoff + j] = p;
            out_C[rowoff + j]  = c;
            costp += p * c;
        }
    }
    #pragma unroll
    for (int off = 32; off > 0; off >>= 1) costp += __shfl_xor(costp, off, 64);
    __syncthreads();               // bs free for reuse
    if (l == 0) bs[wq] = costp;
    __syncthreads();
    if (tid == 0) {
        float s = 0.f;
        #pragma unroll
        for (int g = 0; g < WAVES; ++g) s += bs[g];
        atomicAdd(&out[n], s);
    }
}

extern "C" void kernel_launch(void* const* d_in, const int* in_sizes, int n_in,
                              void* d_out, int out_size, void* d_ws, size_t ws_size,
                              hipStream_t stream) {
    const float* mu = (const float*)d_in[0];
    const float* nu = (const float*)d_in[1];
    const float* C  = (const float*)d_in[2];
    float* out = (float*)d_out;
    u64* zws = (u64*)d_ws;   // NB*ITERS*P*8 = 1.6 MB

    sink_zero<<<(NB * ITERS * P + 1023) / 1024, 1024, 0, stream>>>(zws, out);
    sink_main<<<NB * WPB, THREADS, 0, stream>>>(mu, nu, C, out, zws);
}